// Round 5
// baseline (407.925 us; speedup 1.0000x reference)
//
#include <hip/hip_runtime.h>
#include <hip/hip_bf16.h>

// Transformer block for MI355X. Round 13: split-K flash attention.
//  - r12 post-mortem: pairing long+short blocks balances work but overlap ends
//    when the short one retires -> long block runs solo (occupancy 28%).
//  - r13: qt>=8 k-ranges split in half (flash-decoding); f32 partials (O,m,l)
//    merged by a small kernel. Grid 768 = 3 blocks/CU, triples engineered to
//    sum to exactly 34 k-iters per CU with all members long-lived:
//      block t      (t<256): qt=15-(t>>5), half 0   (qt+1 iters)
//      block 256+t:          qt=15-(t>>5), half 1   (qt+1 iters)
//      block 512+t:          unsplit qt=(t>>5)      (2qt+2 iters)
//  - GEMM/RMSNorm/wprep/splitK-fc2 unchanged from r12.
// All symbols _r13 (fresh build).

typedef __hip_bfloat16 bf16;
typedef __attribute__((ext_vector_type(8))) short short8;   // 8 bf16 = 4 VGPRs
typedef __attribute__((ext_vector_type(4))) float floatx4;  // MFMA C/D frag

__device__ __forceinline__ float bits2f(unsigned short u) {
  union { unsigned int i; float f; } c; c.i = ((unsigned int)u) << 16; return c.f;
}
__device__ __forceinline__ unsigned short f2bits(float f) {
  bf16 b = __float2bfloat16(f);
  union { bf16 b; unsigned short u; } c; c.b = b; return c.u;
}

__device__ __forceinline__ void gld_lds16(const unsigned short* g, unsigned short* l) {
  __builtin_amdgcn_global_load_lds(
      (const __attribute__((address_space(1))) void*)g,
      (__attribute__((address_space(3))) void*)l, 16, 0, 0);
}

// ---------------- RMSNorm: f32 in, f32 gamma, bf16 out ----------------
__global__ __launch_bounds__(256) void rmsnorm_r13(const float* __restrict__ x,
                                                   const float* __restrict__ g,
                                                   unsigned short* __restrict__ out)
{
  const int row = blockIdx.x, tid = threadIdx.x;
  const size_t rb = (size_t)row * 1024;
  float4 xv = *(const float4*)(x + rb + tid * 4);
  float v[4] = {xv.x, xv.y, xv.z, xv.w};
  float s = v[0]*v[0] + v[1]*v[1] + v[2]*v[2] + v[3]*v[3];
  #pragma unroll
  for (int off = 32; off > 0; off >>= 1) s += __shfl_down(s, off, 64);
  __shared__ float part[4];
  if ((tid & 63) == 0) part[tid >> 6] = s;
  __syncthreads();
  const float tot = part[0] + part[1] + part[2] + part[3];
  const float sc = rsqrtf(tot * (1.0f / 1024.0f) + 1.1920929e-07f);
  float4 gv = *(const float4*)(g + tid * 4);
  ushort4 o4 = { f2bits(v[0] * sc * gv.x), f2bits(v[1] * sc * gv.y),
                 f2bits(v[2] * sc * gv.z), f2bits(v[3] * sc * gv.w) };
  *(ushort4*)(out + rb + tid * 4) = o4;
}

// ---------------- Weight prep: W f32 [K,N] -> WT bf16 [N,K] ----------------
__global__ __launch_bounds__(256) void wprep_r13(const float* __restrict__ in,
                                                 unsigned short* __restrict__ out,
                                                 int K, int N)
{
  __shared__ unsigned short tile[32][33];
  const int tid = threadIdx.x;
  const int k0 = blockIdx.y * 32, n0 = blockIdx.x * 32;
  const int tr = tid >> 3, tc4 = (tid & 7) * 4;
  float4 v = *(const float4*)(in + (size_t)(k0 + tr) * N + n0 + tc4);
  tile[tr][tc4 + 0] = f2bits(v.x);
  tile[tr][tc4 + 1] = f2bits(v.y);
  tile[tr][tc4 + 2] = f2bits(v.z);
  tile[tr][tc4 + 3] = f2bits(v.w);
  __syncthreads();
  ushort4 o = { tile[tc4 + 0][tr], tile[tc4 + 1][tr],
                tile[tc4 + 2][tr], tile[tc4 + 3][tr] };
  *(ushort4*)(out + (size_t)(n0 + tr) * K + k0 + tc4) = o;
}

// ---------------- MFMA GEMM: C = A[M,K](bf16) @ BT[N,K]^T(bf16) + bias(f32) ----------------
// 128x128 tile, BK=32, 4 waves each owning a 64x64 quadrant (4x4 MFMA tiles).
// Double-buffered LDS, next-tile DMA issued before compute, one barrier/K-step.
// EPI: 0=bf16  1=f32+resid  2=gelu->bf16  3=f32+resid  4=f32 partial (split-K)
template<int EPI>
__global__ __launch_bounds__(256) void gemm_r13(
    const unsigned short* __restrict__ A,
    const unsigned short* __restrict__ BT,
    const float* __restrict__ bias,
    const float* __restrict__ resid,
    void* __restrict__ Cout,
    int M, int N, int K, int Klen)
{
  __shared__ __align__(16) unsigned short As[2][128 * 32];
  __shared__ __align__(16) unsigned short Bs[2][128 * 32];
  const int tid = threadIdx.x;
  const int lane = tid & 63;
  const int wv = tid >> 6;
  const int m0 = blockIdx.y * 128, n0 = blockIdx.x * 128;
  const int wm = (wv >> 1) * 64, wn = (wv & 1) * 64;
  const int kbase = blockIdx.z * Klen;

  const int s0 = tid, s1 = tid + 256;
  const int r0 = s0 >> 2, kq0 = (s0 & 3) ^ ((r0 >> 1) & 3);
  const int r1 = s1 >> 2, kq1 = (s1 & 3) ^ ((r1 >> 1) & 3);
  const unsigned short* Ab = A  + (size_t)m0 * K;
  const unsigned short* Bb = BT + (size_t)n0 * K;
  const size_t ga0 = (size_t)r0 * K + kq0 * 8 + kbase;
  const size_t ga1 = (size_t)r1 * K + kq1 * 8 + kbase;

  floatx4 acc[4][4];
  #pragma unroll
  for (int i = 0; i < 4; ++i)
    #pragma unroll
    for (int j = 0; j < 4; ++j)
      acc[i][j] = (floatx4){0.f, 0.f, 0.f, 0.f};

  int aoff[4], boff[4];
  #pragma unroll
  for (int i = 0; i < 4; ++i) {
    int ra = wm + i * 16 + (lane & 15);
    aoff[i] = (ra * 4 + ((lane >> 4) ^ ((ra >> 1) & 3))) * 8;
    int rb = wn + i * 16 + (lane & 15);
    boff[i] = (rb * 4 + ((lane >> 4) ^ ((rb >> 1) & 3))) * 8;
  }

  // prologue: stage tile 0 into buf 0
  gld_lds16(Ab + ga0, As[0] + s0 * 8);
  gld_lds16(Ab + ga1, As[0] + s1 * 8);
  gld_lds16(Bb + ga0, Bs[0] + s0 * 8);
  gld_lds16(Bb + ga1, Bs[0] + s1 * 8);
  __syncthreads();

  const int nsteps = Klen >> 5;
  for (int t = 0; t < nsteps; ++t) {
    const int cur = t & 1;
    if (t + 1 < nsteps) {  // issue next-tile DMA; latency hides under MFMAs
      const size_t ko = (size_t)(t + 1) * 32;
      gld_lds16(Ab + ga0 + ko, As[cur ^ 1] + s0 * 8);
      gld_lds16(Ab + ga1 + ko, As[cur ^ 1] + s1 * 8);
      gld_lds16(Bb + ga0 + ko, Bs[cur ^ 1] + s0 * 8);
      gld_lds16(Bb + ga1 + ko, Bs[cur ^ 1] + s1 * 8);
    }

    short8 af[4], bfr[4];
    #pragma unroll
    for (int i = 0; i < 4; ++i) {
      af[i]  = *(const short8*)(As[cur] + aoff[i]);
      bfr[i] = *(const short8*)(Bs[cur] + boff[i]);
    }
    #pragma unroll
    for (int i = 0; i < 4; ++i)
      #pragma unroll
      for (int j = 0; j < 4; ++j)
        acc[i][j] = __builtin_amdgcn_mfma_f32_16x16x32_bf16(af[i], bfr[j], acc[i][j], 0, 0, 0);

    __syncthreads();  // drains next-tile DMA (vmcnt) + read-done for overwrite
  }

  float* Cp32 = (float*)Cout;
  if constexpr (EPI == 4) Cp32 += (size_t)blockIdx.z * ((size_t)M * N);

  #pragma unroll
  for (int i = 0; i < 4; ++i) {
    #pragma unroll
    for (int j = 0; j < 4; ++j) {
      const int rbase = m0 + wm + i * 16 + (lane >> 4) * 4;
      const int c = n0 + wn + j * 16 + (lane & 15);
      float bia = 0.0f;
      if constexpr (EPI != 4) bia = bias[c];
      #pragma unroll
      for (int r = 0; r < 4; ++r) {
        float v = acc[i][j][r] + bia;
        const size_t idx = (size_t)(rbase + r) * N + c;
        if constexpr (EPI == 0) {
          ((unsigned short*)Cout)[idx] = f2bits(v);
        } else if constexpr (EPI == 1) {
          ((float*)Cout)[idx] = v + resid[idx];
        } else if constexpr (EPI == 2) {
          v = 0.5f * v * (1.0f + erff(v * 0.70710678118654752f));
          ((unsigned short*)Cout)[idx] = f2bits(v);
        } else if constexpr (EPI == 3) {
          ((float*)Cout)[idx] = v + resid[idx];
        } else {
          Cp32[idx] = v;  // split-K partial, no bias/resid
        }
      }
    }
  }
}

// ---------------- split-K reduce: out = P0 + P1 + resid + bias ----------------
__global__ __launch_bounds__(256) void red2_r13(const float* __restrict__ P,
                                                const float* __restrict__ resid,
                                                const float* __restrict__ bias,
                                                float* __restrict__ out)
{
  const size_t i = ((size_t)blockIdx.x * 256 + threadIdx.x) * 4;
  const int col = (int)(i & 1023);
  float4 p0 = *(const float4*)(P + i);
  float4 p1 = *(const float4*)(P + ((size_t)4096 * 1024) + i);
  float4 xr = *(const float4*)(resid + i);
  float4 b  = *(const float4*)(bias + col);
  float4 o  = { p0.x + p1.x + xr.x + b.x, p0.y + p1.y + xr.y + b.y,
                p0.z + p1.z + xr.z + b.z, p0.w + p1.w + xr.w + b.w };
  *(float4*)(out + i) = o;
}

// ---------------- MFMA flash attention (r13: split-K, 3 blocks/CU triples) ----------------
// qkv: [B*T, 3072] bf16. o: [B*T,1024] bf16. Opart: f32 [512][128*64].
// MLpart: f32 [512][256] (m[128] then l[128]).
__global__ __launch_bounds__(512) void attn_r13(const unsigned short* __restrict__ qkv,
                                                unsigned short* __restrict__ o,
                                                float* __restrict__ Opart,
                                                float* __restrict__ MLpart)
{
  __shared__ __align__(16) unsigned short Ks[2][64 * 64];    // dbuf, swizzled (Q staged here 1st)
  __shared__ __align__(16) unsigned short VT[2][64 * 72];    // dbuf, [d][tok] pad 72
  __shared__ __align__(16) unsigned short Ps[128 * 72];      // [q][tok] pad 72 (wave-own)
  __shared__ __align__(16) float stat_s[128];                // alpha / l (wave-own)

  const int tid = threadIdx.x, lane = tid & 63, wv = tid >> 6;
  const int quad = lane >> 4, l15 = lane & 15;
  const int bid = blockIdx.x;
  const int t = bid & 255, batch = bid >> 8;
  const int p = t >> 5, bh = t & 31;
  int qt, kt0, ktN, pi = -1;
  if (batch < 2) {               // split halves of qt = 15-p
    qt = 15 - p;
    kt0 = batch ? (qt + 1) : 0;
    ktN = batch ? (2 * qt + 2) : (qt + 1);
    pi = (p * 32 + bh) * 2 + batch;
  } else {                       // unsplit short tiles
    qt = p;
    kt0 = 0;
    ktN = 2 * qt + 2;
  }
  const int b = bh >> 4, h = bh & 15;
  const size_t base = (size_t)b * 2048 * 3072;
  const int qcol = h * 64, kcol = 1024 + h * 64, vcol = 2048 + h * 64;
  const int q0 = qt * 128;

  // loop-invariant staging addresses
  const int sr = tid >> 3, scp = tid & 7, sc = scp ^ (sr & 7);
  const unsigned short* kgp = qkv + base + (size_t)sr * 3072 + kcol + sc * 8;   // + kt*64*3072
  const int vp = tid & 31, vdc = tid >> 5;                                      // tok pair, dim quad
  const unsigned short* vgp = qkv + base + (size_t)(2 * vp) * 3072 + vcol + vdc * 4;

  // ---- stage Q through Ks region (1024 slots of 16B, chunk-XOR swizzle) ----
  unsigned short* Qstage = &Ks[0][0];   // 16KB contiguous
  #pragma unroll
  for (int pp = 0; pp < 2; ++pp) {
    int s = tid + 512 * pp;
    int r = s >> 3, cp = s & 7, c = cp ^ (r & 7);
    gld_lds16(qkv + base + (size_t)(q0 + r) * 3072 + qcol + c * 8, Qstage + s * 8);
  }
  // issue V tile-kt0 global loads (consumed after Q is read out)
  const size_t koff0 = (size_t)kt0 * 64 * 3072;
  uint2 v0a = *(const uint2*)(vgp + koff0);
  uint2 v0b = *(const uint2*)(vgp + koff0 + 3072);
  __syncthreads();   // Q visible in LDS

  // ---- preload Q A-frags into registers (row = wave q-row, k = dim) ----
  short8 qa[2];
  #pragma unroll
  for (int ks = 0; ks < 2; ++ks) {
    int ra = wv * 16 + l15;
    int cp = (ks * 4 + quad) ^ (ra & 7);
    qa[ks] = *(const short8*)(Qstage + (ra * 8 + cp) * 8);
  }
  __syncthreads();   // all waves done reading Q; Ks region reusable

  // ---- stage K tile kt0 (DMA) + write V tile kt0 ----
  gld_lds16(kgp + koff0, Ks[0] + tid * 8);
  {
    unsigned short* dst = VT[0] + (size_t)(vdc * 4) * 72 + 2 * vp;
    *(unsigned int*)(dst + 0 * 72) = (v0a.x & 0xffffu) | (v0b.x << 16);
    *(unsigned int*)(dst + 1 * 72) = (v0a.x >> 16)     | (v0b.x & 0xffff0000u);
    *(unsigned int*)(dst + 2 * 72) = (v0a.y & 0xffffu) | (v0b.y << 16);
    *(unsigned int*)(dst + 3 * 72) = (v0a.y >> 16)     | (v0b.y & 0xffff0000u);
  }
  __syncthreads();

  floatx4 oacc[4];  // O^T accumulator per d-tile
  #pragma unroll
  for (int dt = 0; dt < 4; ++dt) oacc[dt] = (floatx4){0.f, 0.f, 0.f, 0.f};
  float m_i[4], l_i[4];
  #pragma unroll
  for (int r = 0; r < 4; ++r) { m_i[r] = -3.0e38f; l_i[r] = 0.0f; }

  for (int kt = kt0; kt < ktN; ++kt) {
    const int cur = (kt - kt0) & 1;
    const bool pf = (kt + 1 < ktN);
    uint2 u0, u1;
    if (pf) {  // issue next-tile loads NOW; latency hides under compute below
      const size_t koff = (size_t)(kt + 1) * 64 * 3072;
      gld_lds16(kgp + koff, Ks[cur ^ 1] + tid * 8);
      u0 = *(const uint2*)(vgp + koff);
      u1 = *(const uint2*)(vgp + koff + 3072);
    }

    // ---- S = Q K^T (from Ks[cur]) ----
    short8 kb[4][2];
    #pragma unroll
    for (int j = 0; j < 4; ++j)
      #pragma unroll
      for (int ks = 0; ks < 2; ++ks) {
        int rb = j * 16 + l15;
        int cp = (ks * 4 + quad) ^ (rb & 7);
        kb[j][ks] = *(const short8*)(Ks[cur] + (rb * 8 + cp) * 8);
      }
    floatx4 s_[4];
    #pragma unroll
    for (int j = 0; j < 4; ++j) s_[j] = (floatx4){0.f, 0.f, 0.f, 0.f};
    #pragma unroll
    for (int j = 0; j < 4; ++j)
      #pragma unroll
      for (int ks = 0; ks < 2; ++ks)
        s_[j] = __builtin_amdgcn_mfma_f32_16x16x32_bf16(qa[ks], kb[j][ks], s_[j], 0, 0, 0);

    // ---- mask + online softmax (registers) + P write ----
    const int k0 = kt * 64;
    const int rowmin = q0 + wv * 16;
    const int rowb = rowmin + quad * 4;
    if (k0 + 63 > rowmin) {  // diagonal tile: causal mask
      #pragma unroll
      for (int j = 0; j < 4; ++j) {
        const int col = k0 + j * 16 + l15;
        #pragma unroll
        for (int r = 0; r < 4; ++r)
          if (col > rowb + r) s_[j][r] = -3.0e38f;
      }
    }
    float fm[4], al[4], rs[4];
    #pragma unroll
    for (int r = 0; r < 4; ++r)
      fm[r] = fmaxf(fmaxf(s_[0][r], s_[1][r]), fmaxf(s_[2][r], s_[3][r]));
    #pragma unroll
    for (int msk = 1; msk < 16; msk <<= 1)
      #pragma unroll
      for (int r = 0; r < 4; ++r)
        fm[r] = fmaxf(fm[r], __shfl_xor(fm[r], msk, 64));
    #pragma unroll
    for (int r = 0; r < 4; ++r) {
      const float mn = fmaxf(m_i[r], fm[r]);
      al[r] = __expf(m_i[r] - mn);
      m_i[r] = mn;
    }
    #pragma unroll
    for (int j = 0; j < 4; ++j)
      #pragma unroll
      for (int r = 0; r < 4; ++r)
        s_[j][r] = __expf(s_[j][r] - m_i[r]);
    #pragma unroll
    for (int r = 0; r < 4; ++r)
      rs[r] = (s_[0][r] + s_[1][r]) + (s_[2][r] + s_[3][r]);
    #pragma unroll
    for (int msk = 1; msk < 16; msk <<= 1)
      #pragma unroll
      for (int r = 0; r < 4; ++r)
        rs[r] += __shfl_xor(rs[r], msk, 64);
    #pragma unroll
    for (int r = 0; r < 4; ++r)
      l_i[r] = l_i[r] * al[r] + rs[r];
    if (l15 == 0) {  // publish alpha (wave-own rows; same-wave read below)
      float4 a4 = { al[0], al[1], al[2], al[3] };
      *(float4*)(stat_s + wv * 16 + quad * 4) = a4;
    }
    #pragma unroll
    for (int j = 0; j < 4; ++j)
      #pragma unroll
      for (int r = 0; r < 4; ++r)
        Ps[(size_t)(wv * 16 + quad * 4 + r) * 72 + j * 16 + l15] = f2bits(s_[j][r]);

    // ---- O^T += V^T P^T (all wave-local LDS; no extra barrier) ----
    const float alq = stat_s[wv * 16 + l15];
    #pragma unroll
    for (int dt = 0; dt < 4; ++dt)
      #pragma unroll
      for (int r = 0; r < 4; ++r)
        oacc[dt][r] *= alq;

    short8 va[4][2], pb[2];
    #pragma unroll
    for (int dt = 0; dt < 4; ++dt)
      #pragma unroll
      for (int ks = 0; ks < 2; ++ks)
        va[dt][ks] = *(const short8*)(VT[cur] + (size_t)(dt * 16 + l15) * 72 + ks * 32 + quad * 8);
    #pragma unroll
    for (int ks = 0; ks < 2; ++ks)
      pb[ks] = *(const short8*)(Ps + (size_t)(wv * 16 + l15) * 72 + ks * 32 + quad * 8);
    #pragma unroll
    for (int dt = 0; dt < 4; ++dt)
      #pragma unroll
      for (int ks = 0; ks < 2; ++ks)
        oacc[dt] = __builtin_amdgcn_mfma_f32_16x16x32_bf16(va[dt][ks], pb[ks], oacc[dt], 0, 0, 0);

    // ---- late write of prefetched V into the other buffer ----
    if (pf) {
      unsigned short* dst = VT[cur ^ 1] + (size_t)(vdc * 4) * 72 + 2 * vp;
      *(unsigned int*)(dst + 0 * 72) = (u0.x & 0xffffu) | (u1.x << 16);
      *(unsigned int*)(dst + 1 * 72) = (u0.x >> 16)     | (u1.x & 0xffff0000u);
      *(unsigned int*)(dst + 2 * 72) = (u0.y & 0xffffu) | (u1.y << 16);
      *(unsigned int*)(dst + 3 * 72) = (u0.y >> 16)     | (u1.y & 0xffff0000u);
    }
    __syncthreads();  // drains next-K DMA (vmcnt) + makes VT[nxt] visible
  }

  if (batch < 2) {
    // ---- partial epilogue: raw O (f32) + m,l ----
    float* Ob = Opart + (size_t)pi * (128 * 64);
    const int q = wv * 16 + l15;
    #pragma unroll
    for (int dt = 0; dt < 4; ++dt) {
      float4 o4 = { oacc[dt][0], oacc[dt][1], oacc[dt][2], oacc[dt][3] };
      *(float4*)(Ob + q * 64 + dt * 16 + quad * 4) = o4;
    }
    if (l15 == 0) {
      float* Mb = MLpart + (size_t)pi * 256;
      #pragma unroll
      for (int r = 0; r < 4; ++r) {
        Mb[wv * 16 + quad * 4 + r]       = m_i[r];
        Mb[128 + wv * 16 + quad * 4 + r] = l_i[r];
      }
    }
  } else {
    // ---- final epilogue: O = O^T / l * 32^-1 ----
    if (l15 == 0) {
      float4 l4 = { l_i[0], l_i[1], l_i[2], l_i[3] };
      *(float4*)(stat_s + wv * 16 + quad * 4) = l4;
    }
    const float linv = 0.03125f / stat_s[wv * 16 + l15];
    const size_t row = (size_t)b * 2048 + q0 + wv * 16 + l15;
    #pragma unroll
    for (int dt = 0; dt < 4; ++dt) {
      const int col = h * 64 + dt * 16 + quad * 4;
      ushort4 o4 = { f2bits(oacc[dt][0] * linv), f2bits(oacc[dt][1] * linv),
                     f2bits(oacc[dt][2] * linv), f2bits(oacc[dt][3] * linv) };
      *(ushort4*)(o + row * 1024 + col) = o4;
    }
  }
}

// ---------------- attention split merge: combine two halves ----------------
// grid (8, 32): p = blockIdx.x (qt = 15-p), bh = blockIdx.y. 256 threads.
__global__ __launch_bounds__(256) void amerge_r13(const float* __restrict__ Opart,
                                                  const float* __restrict__ MLpart,
                                                  unsigned short* __restrict__ o)
{
  const int p = blockIdx.x, bh = blockIdx.y;
  const int qt = 15 - p, b = bh >> 4, h = bh & 15;
  const int pi0 = (p * 32 + bh) * 2;
  const float* O1 = Opart + (size_t)pi0 * (128 * 64);
  const float* O2 = O1 + 128 * 64;
  const float* ML1 = MLpart + (size_t)pi0 * 256;
  const float* ML2 = ML1 + 256;
  const int tid = threadIdx.x;
  const int q = tid >> 1, d0 = (tid & 1) * 32;
  const float m1 = ML1[q], l1 = ML1[128 + q];
  const float m2 = ML2[q], l2 = ML2[128 + q];
  const float m = fmaxf(m1, m2);
  const float a1 = __expf(m1 - m), a2 = __expf(m2 - m);
  const float inv = 0.03125f / (l1 * a1 + l2 * a2);
  const size_t row = (size_t)b * 2048 + qt * 128 + q;
  unsigned short* ob = o + row * 1024 + h * 64 + d0;
  #pragma unroll
  for (int e = 0; e < 8; ++e) {
    float4 o1 = *(const float4*)(O1 + q * 64 + d0 + e * 4);
    float4 o2 = *(const float4*)(O2 + q * 64 + d0 + e * 4);
    ushort4 o4 = { f2bits((o1.x * a1 + o2.x * a2) * inv),
                   f2bits((o1.y * a1 + o2.y * a2) * inv),
                   f2bits((o1.z * a1 + o2.z * a2) * inv),
                   f2bits((o1.w * a1 + o2.w * a2) * inv) };
    *(ushort4*)(ob + e * 4) = o4;
  }
}

extern "C" void kernel_launch(void* const* d_in, const int* in_sizes, int n_in,
                              void* d_out, int out_size, void* d_ws, size_t ws_size,
                              hipStream_t stream)
{
  (void)in_sizes; (void)n_in; (void)out_size; (void)ws_size;
  const float* x      = (const float*)d_in[0];
  const float* w_attn = (const float*)d_in[1];
  const float* b_attn = (const float*)d_in[2];
  const float* w_proj = (const float*)d_in[3];
  const float* b_proj = (const float*)d_in[4];
  const float* w_fc1  = (const float*)d_in[5];
  const float* b_fc1  = (const float*)d_in[6];
  const float* w_fc2  = (const float*)d_in[7];
  const float* b_fc2  = (const float*)d_in[8];
  const float* g1     = (const float*)d_in[9];
  const float* g2     = (const float*)d_in[10];
  float* out = (float*)d_out;

  // ws layout (88 MB): h/ov bf16 @0 (8MB), qkv bf16 @8MB (24MB, h2 reuses 8..16MB),
  //                    x1 f32 @32MB (16MB), h3 bf16 @48MB (32MB), WT scratch @80MB (8MB)
  // attn split partials (17.3MB) reuse 48..66MB (h3 region, dead during attn).
  // fc2 split-K partials (2 x 16MB f32) reuse 0..32MB (h/h2/qkv/ov all dead there).
  char* ws = (char*)d_ws;
  unsigned short* h   = (unsigned short*)(ws);
  unsigned short* qkv = (unsigned short*)(ws + ((size_t)8  << 20));
  unsigned short* ov  = (unsigned short*)(ws);                       // reuse h
  float*          x1  = (float*)         (ws + ((size_t)32 << 20));
  unsigned short* h2  = (unsigned short*)(ws + ((size_t)8  << 20));  // reuse qkv
  unsigned short* h3  = (unsigned short*)(ws + ((size_t)48 << 20));
  unsigned short* WT  = (unsigned short*)(ws + ((size_t)80 << 20));
  float*          P   = (float*)(ws);                                // fc2 split-K partials
  float*          Op  = (float*)(ws + ((size_t)48 << 20));           // attn O partials (16.78MB)
  float*          MLp = (float*)(ws + ((size_t)65 << 20));           // attn m,l partials (512KB)

  const int M = 4096;

  rmsnorm_r13<<<M, 256, 0, stream>>>(x, g1, h);
  wprep_r13<<<dim3(3072 / 32, 1024 / 32), 256, 0, stream>>>(w_attn, WT, 1024, 3072);
  gemm_r13<0><<<dim3(3072 / 128, M / 128), 256, 0, stream>>>(h, WT, b_attn, nullptr, qkv, M, 3072, 1024, 1024);
  attn_r13<<<dim3(768), 512, 0, stream>>>(qkv, ov, Op, MLp);
  amerge_r13<<<dim3(8, 32), 256, 0, stream>>>(Op, MLp, ov);
  wprep_r13<<<dim3(1024 / 32, 1024 / 32), 256, 0, stream>>>(w_proj, WT, 1024, 1024);
  gemm_r13<1><<<dim3(1024 / 128, M / 128), 256, 0, stream>>>(ov, WT, b_proj, x, x1, M, 1024, 1024, 1024);
  rmsnorm_r13<<<M, 256, 0, stream>>>(x1, g2, h2);
  wprep_r13<<<dim3(4096 / 32, 1024 / 32), 256, 0, stream>>>(w_fc1, WT, 1024, 4096);
  gemm_r13<2><<<dim3(4096 / 128, M / 128), 256, 0, stream>>>(h2, WT, b_fc1, nullptr, h3, M, 4096, 1024, 1024);
  wprep_r13<<<dim3(1024 / 32, 4096 / 32), 256, 0, stream>>>(w_fc2, WT, 4096, 1024);
  gemm_r13<4><<<dim3(1024 / 128, M / 128, 2), 256, 0, stream>>>(h3, WT, nullptr, nullptr, P, M, 1024, 4096, 2048);
  red2_r13<<<4096, 256, 0, stream>>>(P, x1, b_fc2, out);
}

// Round 7
// 379.419 us; speedup vs baseline: 1.0751x; 1.0751x over previous
//
#include <hip/hip_runtime.h>
#include <hip/hip_bf16.h>

// Transformer block for MI355X. Round 15 (= r14 resubmitted after infra
// failure; audited clean against the learn_hip m194-m201 verified pattern):
//  - attn: proven r10 structure (77us): complementary q-tile pair per block,
//    grid(8,32), prefetch pipeline.
//  - gemm256 for qkv + fc1: 256x256 tile, BK=32, 8 waves (2x4) of 128x64
//    output, 4-buffer LDS ring (128KB), counted s_waitcnt vmcnt(8) + raw
//    s_barrier (loads in flight across barriers; never drained to 0 in
//    steady state). 2x arithmetic intensity vs 128².
//  - proj/fc2 on the 128² dbuf kernel; fc2 keeps split-K=2 + red2.
// All symbols _r15 (fresh build).

typedef __hip_bfloat16 bf16;
typedef __attribute__((ext_vector_type(8))) short short8;   // 8 bf16 = 4 VGPRs
typedef __attribute__((ext_vector_type(4))) float floatx4;  // MFMA C/D frag

__device__ __forceinline__ float bits2f(unsigned short u) {
  union { unsigned int i; float f; } c; c.i = ((unsigned int)u) << 16; return c.f;
}
__device__ __forceinline__ unsigned short f2bits(float f) {
  bf16 b = __float2bfloat16(f);
  union { bf16 b; unsigned short u; } c; c.b = b; return c.u;
}

__device__ __forceinline__ void gld_lds16(const unsigned short* g, unsigned short* l) {
  __builtin_amdgcn_global_load_lds(
      (const __attribute__((address_space(1))) void*)g,
      (__attribute__((address_space(3))) void*)l, 16, 0, 0);
}

// ---------------- RMSNorm: f32 in, f32 gamma, bf16 out ----------------
__global__ __launch_bounds__(256) void rmsnorm_r15(const float* __restrict__ x,
                                                   const float* __restrict__ g,
                                                   unsigned short* __restrict__ out)
{
  const int row = blockIdx.x, tid = threadIdx.x;
  const size_t rb = (size_t)row * 1024;
  float4 xv = *(const float4*)(x + rb + tid * 4);
  float v[4] = {xv.x, xv.y, xv.z, xv.w};
  float s = v[0]*v[0] + v[1]*v[1] + v[2]*v[2] + v[3]*v[3];
  #pragma unroll
  for (int off = 32; off > 0; off >>= 1) s += __shfl_down(s, off, 64);
  __shared__ float part[4];
  if ((tid & 63) == 0) part[tid >> 6] = s;
  __syncthreads();
  const float tot = part[0] + part[1] + part[2] + part[3];
  const float sc = rsqrtf(tot * (1.0f / 1024.0f) + 1.1920929e-07f);
  float4 gv = *(const float4*)(g + tid * 4);
  ushort4 o4 = { f2bits(v[0] * sc * gv.x), f2bits(v[1] * sc * gv.y),
                 f2bits(v[2] * sc * gv.z), f2bits(v[3] * sc * gv.w) };
  *(ushort4*)(out + rb + tid * 4) = o4;
}

// ---------------- Weight prep: W f32 [K,N] -> WT bf16 [N,K] ----------------
__global__ __launch_bounds__(256) void wprep_r15(const float* __restrict__ in,
                                                 unsigned short* __restrict__ out,
                                                 int K, int N)
{
  __shared__ unsigned short tile[32][33];
  const int tid = threadIdx.x;
  const int k0 = blockIdx.y * 32, n0 = blockIdx.x * 32;
  const int tr = tid >> 3, tc4 = (tid & 7) * 4;
  float4 v = *(const float4*)(in + (size_t)(k0 + tr) * N + n0 + tc4);
  tile[tr][tc4 + 0] = f2bits(v.x);
  tile[tr][tc4 + 1] = f2bits(v.y);
  tile[tr][tc4 + 2] = f2bits(v.z);
  tile[tr][tc4 + 3] = f2bits(v.w);
  __syncthreads();
  ushort4 o = { tile[tc4 + 0][tr], tile[tc4 + 1][tr],
                tile[tc4 + 2][tr], tile[tc4 + 3][tr] };
  *(ushort4*)(out + (size_t)(n0 + tr) * K + k0 + tc4) = o;
}

// ---------------- 128x128 MFMA GEMM (proj / fc2-splitK) ----------------
// EPI: 0=bf16  1=f32+resid  2=gelu->bf16  3=f32+resid  4=f32 partial (split-K)
template<int EPI>
__global__ __launch_bounds__(256) void gemm128_r15(
    const unsigned short* __restrict__ A,
    const unsigned short* __restrict__ BT,
    const float* __restrict__ bias,
    const float* __restrict__ resid,
    void* __restrict__ Cout,
    int M, int N, int K, int Klen)
{
  __shared__ __align__(16) unsigned short As[2][128 * 32];
  __shared__ __align__(16) unsigned short Bs[2][128 * 32];
  const int tid = threadIdx.x;
  const int lane = tid & 63;
  const int wv = tid >> 6;
  const int m0 = blockIdx.y * 128, n0 = blockIdx.x * 128;
  const int wm = (wv >> 1) * 64, wn = (wv & 1) * 64;
  const int kbase = blockIdx.z * Klen;

  const int s0 = tid, s1 = tid + 256;
  const int r0 = s0 >> 2, kq0 = (s0 & 3) ^ ((r0 >> 1) & 3);
  const int r1 = s1 >> 2, kq1 = (s1 & 3) ^ ((r1 >> 1) & 3);
  const unsigned short* Ab = A  + (size_t)m0 * K;
  const unsigned short* Bb = BT + (size_t)n0 * K;
  const size_t ga0 = (size_t)r0 * K + kq0 * 8 + kbase;
  const size_t ga1 = (size_t)r1 * K + kq1 * 8 + kbase;

  floatx4 acc[4][4];
  #pragma unroll
  for (int i = 0; i < 4; ++i)
    #pragma unroll
    for (int j = 0; j < 4; ++j)
      acc[i][j] = (floatx4){0.f, 0.f, 0.f, 0.f};

  int aoff[4], boff[4];
  #pragma unroll
  for (int i = 0; i < 4; ++i) {
    int ra = wm + i * 16 + (lane & 15);
    aoff[i] = (ra * 4 + ((lane >> 4) ^ ((ra >> 1) & 3))) * 8;
    int rb = wn + i * 16 + (lane & 15);
    boff[i] = (rb * 4 + ((lane >> 4) ^ ((rb >> 1) & 3))) * 8;
  }

  gld_lds16(Ab + ga0, As[0] + s0 * 8);
  gld_lds16(Ab + ga1, As[0] + s1 * 8);
  gld_lds16(Bb + ga0, Bs[0] + s0 * 8);
  gld_lds16(Bb + ga1, Bs[0] + s1 * 8);
  __syncthreads();

  const int nsteps = Klen >> 5;
  for (int t = 0; t < nsteps; ++t) {
    const int cur = t & 1;
    if (t + 1 < nsteps) {
      const size_t ko = (size_t)(t + 1) * 32;
      gld_lds16(Ab + ga0 + ko, As[cur ^ 1] + s0 * 8);
      gld_lds16(Ab + ga1 + ko, As[cur ^ 1] + s1 * 8);
      gld_lds16(Bb + ga0 + ko, Bs[cur ^ 1] + s0 * 8);
      gld_lds16(Bb + ga1 + ko, Bs[cur ^ 1] + s1 * 8);
    }

    short8 af[4], bfr[4];
    #pragma unroll
    for (int i = 0; i < 4; ++i) {
      af[i]  = *(const short8*)(As[cur] + aoff[i]);
      bfr[i] = *(const short8*)(Bs[cur] + boff[i]);
    }
    #pragma unroll
    for (int i = 0; i < 4; ++i)
      #pragma unroll
      for (int j = 0; j < 4; ++j)
        acc[i][j] = __builtin_amdgcn_mfma_f32_16x16x32_bf16(af[i], bfr[j], acc[i][j], 0, 0, 0);

    __syncthreads();
  }

  float* Cp32 = (float*)Cout;
  if constexpr (EPI == 4) Cp32 += (size_t)blockIdx.z * ((size_t)M * N);

  #pragma unroll
  for (int i = 0; i < 4; ++i) {
    #pragma unroll
    for (int j = 0; j < 4; ++j) {
      const int rbase = m0 + wm + i * 16 + (lane >> 4) * 4;
      const int c = n0 + wn + j * 16 + (lane & 15);
      float bia = 0.0f;
      if constexpr (EPI != 4) bia = bias[c];
      #pragma unroll
      for (int r = 0; r < 4; ++r) {
        float v = acc[i][j][r] + bia;
        const size_t idx = (size_t)(rbase + r) * N + c;
        if constexpr (EPI == 0) {
          ((unsigned short*)Cout)[idx] = f2bits(v);
        } else if constexpr (EPI == 1) {
          ((float*)Cout)[idx] = v + resid[idx];
        } else if constexpr (EPI == 2) {
          v = 0.5f * v * (1.0f + erff(v * 0.70710678118654752f));
          ((unsigned short*)Cout)[idx] = f2bits(v);
        } else if constexpr (EPI == 3) {
          ((float*)Cout)[idx] = v + resid[idx];
        } else {
          Cp32[idx] = v;
        }
      }
    }
  }
}

// ---------------- 256x256 MFMA GEMM (qkv / fc1): 4-ring + counted vmcnt ----------------
// 512 threads = 8 waves (2M x 4N), each owns 128x64 output (8x4 MFMA tiles).
// BK=32. LDS = 4 ring buffers x (A 16KB + B 16KB) = 128KB. Prologue stages
// tiles 0,1; step t issues tile t+2 then waits vmcnt(8) (oldest 4 = tile t
// retired, 8 in flight) + raw s_barrier. Never drains to 0 in steady state.
// Ring safety: buffer read at step t is rewritten by STG at t+2; the t+1
// barrier happens-after step-t MFMAs (whose lgkmcnt waits ensure reads done).
// EPI: 0=bf16+bias  2=gelu->bf16.
template<int EPI>
__global__ __launch_bounds__(512) void gemm256_r15(
    const unsigned short* __restrict__ A,
    const unsigned short* __restrict__ BT,
    const float* __restrict__ bias,
    void* __restrict__ Cout,
    int M, int N, int K)
{
  __shared__ __align__(16) unsigned short As[4][256 * 32];
  __shared__ __align__(16) unsigned short Bs[4][256 * 32];
  const int tid = threadIdx.x;
  const int lane = tid & 63, wv = tid >> 6;
  const int quad = lane >> 4, l15 = lane & 15;
  const int m0 = blockIdx.y * 256, n0 = blockIdx.x * 256;
  const int wm = (wv >> 2) * 128, wn = (wv & 3) * 64;

  const int s0 = tid, s1 = tid + 512;
  const int r0 = s0 >> 2, kq0 = (s0 & 3) ^ ((r0 >> 1) & 3);
  const int r1 = s1 >> 2, kq1 = (s1 & 3) ^ ((r1 >> 1) & 3);
  const unsigned short* Ab = A  + (size_t)m0 * K;
  const unsigned short* Bb = BT + (size_t)n0 * K;
  const size_t ga0 = (size_t)r0 * K + kq0 * 8;
  const size_t ga1 = (size_t)r1 * K + kq1 * 8;

  floatx4 acc[8][4];
  #pragma unroll
  for (int i = 0; i < 8; ++i)
    #pragma unroll
    for (int j = 0; j < 4; ++j)
      acc[i][j] = (floatx4){0.f, 0.f, 0.f, 0.f};

  int aoff[8], boff[4];
  #pragma unroll
  for (int i = 0; i < 8; ++i) {
    int ra = wm + i * 16 + l15;
    aoff[i] = (ra * 4 + (quad ^ ((ra >> 1) & 3))) * 8;
  }
  #pragma unroll
  for (int j = 0; j < 4; ++j) {
    int rb = wn + j * 16 + l15;
    boff[j] = (rb * 4 + (quad ^ ((rb >> 1) & 3))) * 8;
  }

  #define STG_R15(t) { const size_t ko = (size_t)(t) * 32; const int bb = (t) & 3; \
    gld_lds16(Ab + ga0 + ko, As[bb] + s0 * 8); \
    gld_lds16(Ab + ga1 + ko, As[bb] + s1 * 8); \
    gld_lds16(Bb + ga0 + ko, Bs[bb] + s0 * 8); \
    gld_lds16(Bb + ga1 + ko, Bs[bb] + s1 * 8); }

  STG_R15(0);
  STG_R15(1);

  const int nsteps = K >> 5;
  for (int t = 0; t < nsteps; ++t) {
    const int cur = t & 3;
    if (t + 2 < nsteps) {
      STG_R15(t + 2);
      asm volatile("s_waitcnt vmcnt(8)" ::: "memory");   // tile t landed; t+1,t+2 in flight
    } else if (t + 1 < nsteps) {
      asm volatile("s_waitcnt vmcnt(4)" ::: "memory");   // tile t landed; t+1 in flight
    } else {
      asm volatile("s_waitcnt vmcnt(0)" ::: "memory");   // last tile
    }
    __builtin_amdgcn_s_barrier();
    asm volatile("" ::: "memory");   // keep LDS reads below the barrier

    short8 bfr[4];
    #pragma unroll
    for (int j = 0; j < 4; ++j)
      bfr[j] = *(const short8*)(Bs[cur] + boff[j]);
    #pragma unroll
    for (int ih = 0; ih < 2; ++ih) {
      short8 af[4];
      #pragma unroll
      for (int k = 0; k < 4; ++k)
        af[k] = *(const short8*)(As[cur] + aoff[ih * 4 + k]);
      #pragma unroll
      for (int k = 0; k < 4; ++k)
        #pragma unroll
        for (int j = 0; j < 4; ++j)
          acc[ih * 4 + k][j] = __builtin_amdgcn_mfma_f32_16x16x32_bf16(af[k], bfr[j], acc[ih * 4 + k][j], 0, 0, 0);
    }
  }
  #undef STG_R15

  #pragma unroll
  for (int i = 0; i < 8; ++i) {
    #pragma unroll
    for (int j = 0; j < 4; ++j) {
      const int rbase = m0 + wm + i * 16 + quad * 4;
      const int c = n0 + wn + j * 16 + l15;
      const float bia = bias[c];
      #pragma unroll
      for (int r = 0; r < 4; ++r) {
        float v = acc[i][j][r] + bia;
        const size_t idx = (size_t)(rbase + r) * N + c;
        if constexpr (EPI == 2) {
          v = 0.5f * v * (1.0f + erff(v * 0.70710678118654752f));
        }
        ((unsigned short*)Cout)[idx] = f2bits(v);
      }
    }
  }
}

// ---------------- split-K reduce: out = P0 + P1 + resid + bias ----------------
__global__ __launch_bounds__(256) void red2_r15(const float* __restrict__ P,
                                                const float* __restrict__ resid,
                                                const float* __restrict__ bias,
                                                float* __restrict__ out)
{
  const size_t i = ((size_t)blockIdx.x * 256 + threadIdx.x) * 4;
  const int col = (int)(i & 1023);
  float4 p0 = *(const float4*)(P + i);
  float4 p1 = *(const float4*)(P + ((size_t)4096 * 1024) + i);
  float4 xr = *(const float4*)(resid + i);
  float4 b  = *(const float4*)(bias + col);
  float4 o  = { p0.x + p1.x + xr.x + b.x, p0.y + p1.y + xr.y + b.y,
                p0.z + p1.z + xr.z + b.z, p0.w + p1.w + xr.w + b.w };
  *(float4*)(out + i) = o;
}

// ---------------- MFMA flash attention (r10 structure, verbatim) ----------------
__global__ __launch_bounds__(512) void attn_r15(const unsigned short* __restrict__ qkv,
                                                unsigned short* __restrict__ o)
{
  __shared__ __align__(16) unsigned short Qs[128 * 64];
  __shared__ __align__(16) unsigned short Ks[2][64 * 64];
  __shared__ __align__(16) unsigned short VT[2][64 * 72];
  __shared__ __align__(16) unsigned short Ps[128 * 72];
  __shared__ __align__(16) float stat_s[128];

  const int tid = threadIdx.x, lane = tid & 63, wv = tid >> 6;
  const int quad = lane >> 4, l15 = lane & 15;
  const int qt0 = blockIdx.x, bh = blockIdx.y;
  const int b = bh >> 4, h = bh & 15;
  const size_t base = (size_t)b * 2048 * 3072;
  const int qcol = h * 64, kcol = 1024 + h * 64, vcol = 2048 + h * 64;

  const int sr = tid >> 3, scp = tid & 7, sc = scp ^ (sr & 7);
  const unsigned short* kgp = qkv + base + (size_t)sr * 3072 + kcol + sc * 8;
  const int vp = tid & 31, vdc = tid >> 5;
  const unsigned short* vgp = qkv + base + (size_t)(2 * vp) * 3072 + vcol + vdc * 4;

  for (int pass = 0; pass < 2; ++pass) {
    const int qt = pass ? qt0 : 15 - qt0;
    const int q0 = qt * 128;
    const int nkt = 2 * qt + 2;

    __syncthreads();

    #pragma unroll
    for (int p = 0; p < 2; ++p) {
      int s = tid + 512 * p;
      int r = s >> 3, cp = s & 7, c = cp ^ (r & 7);
      gld_lds16(qkv + base + (size_t)(q0 + r) * 3072 + qcol + c * 8, Qs + s * 8);
    }
    gld_lds16(kgp, Ks[0] + tid * 8);
    {
      uint2 u0 = *(const uint2*)vgp;
      uint2 u1 = *(const uint2*)(vgp + 3072);
      unsigned short* dst = VT[0] + (size_t)(vdc * 4) * 72 + 2 * vp;
      *(unsigned int*)(dst + 0 * 72) = (u0.x & 0xffffu) | (u1.x << 16);
      *(unsigned int*)(dst + 1 * 72) = (u0.x >> 16)     | (u1.x & 0xffff0000u);
      *(unsigned int*)(dst + 2 * 72) = (u0.y & 0xffffu) | (u1.y << 16);
      *(unsigned int*)(dst + 3 * 72) = (u0.y >> 16)     | (u1.y & 0xffff0000u);
    }
    __syncthreads();

    short8 qa[2];
    #pragma unroll
    for (int ks = 0; ks < 2; ++ks) {
      int ra = wv * 16 + l15;
      int cp = (ks * 4 + quad) ^ (ra & 7);
      qa[ks] = *(const short8*)(Qs + (ra * 8 + cp) * 8);
    }

    floatx4 oacc[4];
    #pragma unroll
    for (int dt = 0; dt < 4; ++dt) oacc[dt] = (floatx4){0.f, 0.f, 0.f, 0.f};
    float m_i[4], l_i[4];
    #pragma unroll
    for (int r = 0; r < 4; ++r) { m_i[r] = -3.0e38f; l_i[r] = 0.0f; }

    for (int kt = 0; kt < nkt; ++kt) {
      const int cur = kt & 1;
      const bool pf = (kt + 1 < nkt);
      uint2 u0, u1;
      if (pf) {
        const size_t koff = (size_t)(kt + 1) * 64 * 3072;
        gld_lds16(kgp + koff, Ks[cur ^ 1] + tid * 8);
        u0 = *(const uint2*)(vgp + koff);
        u1 = *(const uint2*)(vgp + koff + 3072);
      }

      short8 kb[4][2];
      #pragma unroll
      for (int j = 0; j < 4; ++j)
        #pragma unroll
        for (int ks = 0; ks < 2; ++ks) {
          int rb = j * 16 + l15;
          int cp = (ks * 4 + quad) ^ (rb & 7);
          kb[j][ks] = *(const short8*)(Ks[cur] + (rb * 8 + cp) * 8);
        }
      floatx4 s_[4];
      #pragma unroll
      for (int j = 0; j < 4; ++j) s_[j] = (floatx4){0.f, 0.f, 0.f, 0.f};
      #pragma unroll
      for (int j = 0; j < 4; ++j)
        #pragma unroll
        for (int ks = 0; ks < 2; ++ks)
          s_[j] = __builtin_amdgcn_mfma_f32_16x16x32_bf16(qa[ks], kb[j][ks], s_[j], 0, 0, 0);

      const int k0 = kt * 64;
      const int rowmin = q0 + wv * 16;
      const int rowb = rowmin + quad * 4;
      if (k0 + 63 > rowmin) {
        #pragma unroll
        for (int j = 0; j < 4; ++j) {
          const int col = k0 + j * 16 + l15;
          #pragma unroll
          for (int r = 0; r < 4; ++r)
            if (col > rowb + r) s_[j][r] = -3.0e38f;
        }
      }
      float fm[4], al[4], rs[4];
      #pragma unroll
      for (int r = 0; r < 4; ++r)
        fm[r] = fmaxf(fmaxf(s_[0][r], s_[1][r]), fmaxf(s_[2][r], s_[3][r]));
      #pragma unroll
      for (int msk = 1; msk < 16; msk <<= 1)
        #pragma unroll
        for (int r = 0; r < 4; ++r)
          fm[r] = fmaxf(fm[r], __shfl_xor(fm[r], msk, 64));
      #pragma unroll
      for (int r = 0; r < 4; ++r) {
        const float mn = fmaxf(m_i[r], fm[r]);
        al[r] = __expf(m_i[r] - mn);
        m_i[r] = mn;
      }
      #pragma unroll
      for (int j = 0; j < 4; ++j)
        #pragma unroll
        for (int r = 0; r < 4; ++r)
          s_[j][r] = __expf(s_[j][r] - m_i[r]);
      #pragma unroll
      for (int r = 0; r < 4; ++r)
        rs[r] = (s_[0][r] + s_[1][r]) + (s_[2][r] + s_[3][r]);
      #pragma unroll
      for (int msk = 1; msk < 16; msk <<= 1)
        #pragma unroll
        for (int r = 0; r < 4; ++r)
          rs[r] += __shfl_xor(rs[r], msk, 64);
      #pragma unroll
      for (int r = 0; r < 4; ++r)
        l_i[r] = l_i[r] * al[r] + rs[r];
      if (l15 == 0) {
        float4 a4 = { al[0], al[1], al[2], al[3] };
        *(float4*)(stat_s + wv * 16 + quad * 4) = a4;
      }
      #pragma unroll
      for (int j = 0; j < 4; ++j)
        #pragma unroll
        for (int r = 0; r < 4; ++r)
          Ps[(size_t)(wv * 16 + quad * 4 + r) * 72 + j * 16 + l15] = f2bits(s_[j][r]);

      const float alq = stat_s[wv * 16 + l15];
      #pragma unroll
      for (int dt = 0; dt < 4; ++dt)
        #pragma unroll
        for (int r = 0; r < 4; ++r)
          oacc[dt][r] *= alq;

      short8 va[4][2], pb[2];
      #pragma unroll
      for (int dt = 0; dt < 4; ++dt)
        #pragma unroll
        for (int ks = 0; ks < 2; ++ks)
          va[dt][ks] = *(const short8*)(VT[cur] + (size_t)(dt * 16 + l15) * 72 + ks * 32 + quad * 8);
      #pragma unroll
      for (int ks = 0; ks < 2; ++ks)
        pb[ks] = *(const short8*)(Ps + (size_t)(wv * 16 + l15) * 72 + ks * 32 + quad * 8);
      #pragma unroll
      for (int dt = 0; dt < 4; ++dt)
        #pragma unroll
        for (int ks = 0; ks < 2; ++ks)
          oacc[dt] = __builtin_amdgcn_mfma_f32_16x16x32_bf16(va[dt][ks], pb[ks], oacc[dt], 0, 0, 0);

      if (pf) {
        unsigned short* dst = VT[cur ^ 1] + (size_t)(vdc * 4) * 72 + 2 * vp;
        *(unsigned int*)(dst + 0 * 72) = (u0.x & 0xffffu) | (u1.x << 16);
        *(unsigned int*)(dst + 1 * 72) = (u0.x >> 16)     | (u1.x & 0xffff0000u);
        *(unsigned int*)(dst + 2 * 72) = (u0.y & 0xffffu) | (u1.y << 16);
        *(unsigned int*)(dst + 3 * 72) = (u0.y >> 16)     | (u1.y & 0xffff0000u);
      }
      __syncthreads();
    }

    if (l15 == 0) {
      float4 l4 = { l_i[0], l_i[1], l_i[2], l_i[3] };
      *(float4*)(stat_s + wv * 16 + quad * 4) = l4;
    }
    const float linv = 0.03125f / stat_s[wv * 16 + l15];
    const size_t row = (size_t)b * 2048 + q0 + wv * 16 + l15;
    #pragma unroll
    for (int dt = 0; dt < 4; ++dt) {
      const int col = h * 64 + dt * 16 + quad * 4;
      ushort4 o4 = { f2bits(oacc[dt][0] * linv), f2bits(oacc[dt][1] * linv),
                     f2bits(oacc[dt][2] * linv), f2bits(oacc[dt][3] * linv) };
      *(ushort4*)(o + row * 1024 + col) = o4;
    }
  }
}

extern "C" void kernel_launch(void* const* d_in, const int* in_sizes, int n_in,
                              void* d_out, int out_size, void* d_ws, size_t ws_size,
                              hipStream_t stream)
{
  (void)in_sizes; (void)n_in; (void)out_size; (void)ws_size;
  const float* x      = (const float*)d_in[0];
  const float* w_attn = (const float*)d_in[1];
  const float* b_attn = (const float*)d_in[2];
  const float* w_proj = (const float*)d_in[3];
  const float* b_proj = (const float*)d_in[4];
  const float* w_fc1  = (const float*)d_in[5];
  const float* b_fc1  = (const float*)d_in[6];
  const float* w_fc2  = (const float*)d_in[7];
  const float* b_fc2  = (const float*)d_in[8];
  const float* g1     = (const float*)d_in[9];
  const float* g2     = (const float*)d_in[10];
  float* out = (float*)d_out;

  // ws layout (88 MB): h/ov bf16 @0 (8MB), qkv bf16 @8MB (24MB, h2 reuses 8..16MB),
  //                    x1 f32 @32MB (16MB), h3 bf16 @48MB (32MB), WT scratch @80MB (8MB)
  // fc2 split-K partials (2 x 16MB f32) reuse 0..32MB (h/h2/qkv/ov all dead there).
  char* ws = (char*)d_ws;
  unsigned short* h   = (unsigned short*)(ws);
  unsigned short* qkv = (unsigned short*)(ws + ((size_t)8  << 20));
  unsigned short* ov  = (unsigned short*)(ws);                       // reuse h
  float*          x1  = (float*)         (ws + ((size_t)32 << 20));
  unsigned short* h2  = (unsigned short*)(ws + ((size_t)8  << 20));  // reuse qkv
  unsigned short* h3  = (unsigned short*)(ws + ((size_t)48 << 20));
  unsigned short* WT  = (unsigned short*)(ws + ((size_t)80 << 20));
  float*          P   = (float*)(ws);                                // fc2 split-K partials

  const int M = 4096;

  rmsnorm_r15<<<M, 256, 0, stream>>>(x, g1, h);
  wprep_r15<<<dim3(3072 / 32, 1024 / 32), 256, 0, stream>>>(w_attn, WT, 1024, 3072);
  gemm256_r15<0><<<dim3(3072 / 256, M / 256), 512, 0, stream>>>(h, WT, b_attn, qkv, M, 3072, 1024);
  attn_r15<<<dim3(8, 32), 512, 0, stream>>>(qkv, ov);
  wprep_r15<<<dim3(1024 / 32, 1024 / 32), 256, 0, stream>>>(w_proj, WT, 1024, 1024);
  gemm128_r15<1><<<dim3(1024 / 128, M / 128), 256, 0, stream>>>(ov, WT, b_proj, x, x1, M, 1024, 1024, 1024);
  rmsnorm_r15<<<M, 256, 0, stream>>>(x1, g2, h2);
  wprep_r15<<<dim3(4096 / 32, 1024 / 32), 256, 0, stream>>>(w_fc1, WT, 1024, 4096);
  gemm256_r15<2><<<dim3(4096 / 256, M / 256), 512, 0, stream>>>(h2, WT, b_fc1, h3, M, 4096, 1024);
  wprep_r15<<<dim3(1024 / 32, 4096 / 32), 256, 0, stream>>>(w_fc2, WT, 4096, 1024);
  gemm128_r15<4><<<dim3(1024 / 128, M / 128, 2), 256, 0, stream>>>(h3, WT, nullptr, nullptr, P, M, 1024, 4096, 2048);
  red2_r15<<<4096, 256, 0, stream>>>(P, x1, b_fc2, out);
}